// Round 4
// baseline (242.728 us; speedup 1.0000x reference)
//
#include <hip/hip_runtime.h>
#include <hip/hip_bf16.h>
#include <cstdint>

#define TT   8192
#define KOBS 512
#define HID  2048
#define NOBJ 8
#define NCH  64     // number of time chunks
#define CT   128    // chunk length (TT / NCH)

typedef unsigned short u16;
typedef uint32_t u32;
typedef short bf16x8 __attribute__((ext_vector_type(8)));
typedef float f32x4  __attribute__((ext_vector_type(4)));

static __device__ __forceinline__ float bf2f(u16 u) {
    union { uint32_t i; float f; } v;
    v.i = ((uint32_t)u) << 16;
    return v.f;
}
static __device__ __forceinline__ u16 f2bf(float f) {
    union { float f; uint32_t i; } v;
    v.f = f;
    uint32_t lsb = (v.i >> 16) & 1u;
    uint32_t r = v.i + 0x7fffu + lsb;   // round-to-nearest-even
    return (u16)(r >> 16);
}

// async global->LDS DMA, 16 bytes per lane (wave-uniform base + lane*16).
static __device__ __forceinline__ void async_ld16(const u16* g, u16* l) {
    __builtin_amdgcn_global_load_lds(
        (const __attribute__((address_space(1))) uint32_t*)g,
        (__attribute__((address_space(3))) uint32_t*)l,
        16, 0, 0);
}

// ---------------------------------------------------------------------------
// Kernel 1: cast x -> bf16; cast + row-interleave the 4 weight matrices
// (row n = 4*h + proj, proj: 0=W_in 1=W_B 2=W_C 3=W_delta);
// A_e[h] = -exp(A_log[h]) * log2(e).
// ---------------------------------------------------------------------------
__global__ void prep_kernel(const float* __restrict__ x,
                            const float* __restrict__ Win,
                            const float* __restrict__ WB,
                            const float* __restrict__ WC,
                            const float* __restrict__ Wd,
                            const float* __restrict__ A_log,
                            u16* __restrict__ x_bf,
                            u16* __restrict__ W_bf,
                            float* __restrict__ A_e)
{
    const int64_t NX = (int64_t)TT * KOBS;
    const int64_t NW = (int64_t)4 * HID * KOBS;
    int64_t i = (int64_t)blockIdx.x * blockDim.x + threadIdx.x;
    int64_t stride = (int64_t)gridDim.x * blockDim.x;

    for (int64_t t = i; t < NX; t += stride) x_bf[t] = f2bf(x[t]);

    for (int64_t t = i; t < NW; t += stride) {
        int n = (int)(t >> 9);
        int k = (int)(t & 511);
        int h = n >> 2;
        int w = n & 3;
        const float* src = (w == 0) ? Win : (w == 1) ? WB : (w == 2) ? WC : Wd;
        W_bf[t] = f2bf(src[(int64_t)h * KOBS + k]);
    }

    for (int64_t t = i; t < HID; t += stride)
        A_e[t] = -__expf(A_log[t]) * 1.44269504f;
}

// ---------------------------------------------------------------------------
// Kernel 2: out[t,:] = b_out + x[t,:] @ W_skip.T   (base for atomics)
// ---------------------------------------------------------------------------
__launch_bounds__(256)
__global__ void init_out(const float* __restrict__ x,
                         const float* __restrict__ b_out,
                         const float* __restrict__ W_skip,
                         float* __restrict__ out)
{
    const int wave = threadIdx.x >> 6;
    const int lane = threadIdx.x & 63;
    const int t0 = (blockIdx.x * 4 + wave) * 4;

    float acc[4][NOBJ];
#pragma unroll
    for (int tt = 0; tt < 4; tt++)
#pragma unroll
        for (int o = 0; o < NOBJ; o++) acc[tt][o] = 0.f;

#pragma unroll
    for (int i = 0; i < 2; i++) {
        const int kv = (i * 64 + lane) * 4;
        float4 w[NOBJ];
#pragma unroll
        for (int o = 0; o < NOBJ; o++)
            w[o] = *(const float4*)(W_skip + (size_t)o * KOBS + kv);
#pragma unroll
        for (int tt = 0; tt < 4; tt++) {
            float4 xv = *(const float4*)(x + (size_t)(t0 + tt) * KOBS + kv);
#pragma unroll
            for (int o = 0; o < NOBJ; o++)
                acc[tt][o] += xv.x * w[o].x + xv.y * w[o].y +
                              xv.z * w[o].z + xv.w * w[o].w;
        }
    }
#pragma unroll
    for (int s = 32; s > 0; s >>= 1)
#pragma unroll
        for (int tt = 0; tt < 4; tt++)
#pragma unroll
            for (int o = 0; o < NOBJ; o++)
                acc[tt][o] += __shfl_xor(acc[tt][o], s, 64);
    if (lane == 0) {
#pragma unroll
        for (int tt = 0; tt < 4; tt++)
#pragma unroll
            for (int o = 0; o < NOBJ; o++)
                out[(size_t)(t0 + tt) * NOBJ + o] = acc[tt][o] + b_out[o];
    }
}

// ---------------------------------------------------------------------------
// Kernel 3: fused GEMM + elementwise + scan-pass1.
// A operand = W rows (n-dim) -> D row (4fq+reg) = n, reg = projection.
// Epilogue: pack (la<<16)|bx -> epL (u32, stride 36), cc -> epC (u16, 40);
// packed b128 store-back; pass1 P,S from epL in LDS.
// ---------------------------------------------------------------------------
__launch_bounds__(256)
__global__ void gemm_fused(const u16* __restrict__ x_bf,
                           const u16* __restrict__ W_bf,
                           const float* __restrict__ A_e,
                           u32* __restrict__ LABX,
                           u16* __restrict__ CCg,
                           float* __restrict__ P,
                           float* __restrict__ S)
{
    // union: staging (16 KB) / epilogue epL 18432 B + epC 10240 B = 28672 B
    __shared__ __align__(16) u32 smem32[7168];
    __shared__ float Ps[256], Ss[256];
    u16* a_s = (u16*)smem32;          // x tile  128 x 32
    u16* b_s = a_s + 4096;            // W tile  128 x 32
    u32* epL = smem32;                // [128][36] u32
    u16* epC = (u16*)(smem32 + 4608); // [128][40] u16

    const int tid  = threadIdx.x;
    const int bm   = blockIdx.x & 63;    // t-chunk (== scan chunk)
    const int bn   = blockIdx.x >> 6;    // channel group (32 h)
    const int m0t  = bm * 128;
    const int n0   = bn * 128;
    const int lane = tid & 63;
    const int wave = tid >> 6;
    const int wn   = (wave & 1) * 64;
    const int wt   = (wave >> 1) * 64;
    const int fr   = lane & 15;
    const int fq   = lane >> 4;

    f32x4 acc[4][4];
#pragma unroll
    for (int i = 0; i < 4; i++)
#pragma unroll
        for (int j = 0; j < 4; j++) {
            f32x4 z = {0.f, 0.f, 0.f, 0.f};
            acc[i][j] = z;
        }

    const int srow = tid >> 2;
    const int scg  = (tid & 3) ^ ((srow >> 1) & 3);
    const u16* gA0 = x_bf + (size_t)(m0t + srow) * KOBS + scg * 8;
    const u16* gA1 = gA0 + (size_t)64 * KOBS;
    const u16* gB0 = W_bf + (size_t)(n0 + srow) * KOBS + scg * 8;
    const u16* gB1 = gB0 + (size_t)64 * KOBS;
    u16* lA0 = &a_s[tid * 8];
    u16* lA1 = &a_s[2048 + tid * 8];
    u16* lB0 = &b_s[tid * 8];
    u16* lB1 = &b_s[2048 + tid * 8];

    const int pcg = fq ^ ((fr >> 1) & 3);

    for (int kb = 0; kb < KOBS; kb += 32) {
        async_ld16(gA0 + kb, lA0);
        async_ld16(gA1 + kb, lA1);
        async_ld16(gB0 + kb, lB0);
        async_ld16(gB1 + kb, lB1);
        __syncthreads();

        bf16x8 af[4], bfx[4];
#pragma unroll
        for (int i = 0; i < 4; i++)
            af[i] = *(const bf16x8*)&b_s[(wn + i * 16 + fr) * 32 + pcg * 8];
#pragma unroll
        for (int j = 0; j < 4; j++)
            bfx[j] = *(const bf16x8*)&a_s[(wt + j * 16 + fr) * 32 + pcg * 8];

#pragma unroll
        for (int i = 0; i < 4; i++)
#pragma unroll
            for (int j = 0; j < 4; j++)
                acc[i][j] = __builtin_amdgcn_mfma_f32_16x16x32_bf16(
                    af[i], bfx[j], acc[i][j], 0, 0, 0);
        __syncthreads();
    }

    // epilogue: D row = wn + i*16 + 4*fq + reg (reg=proj), col = wt+j*16+fr
    const int hq = wn >> 2;
#pragma unroll
    for (int i = 0; i < 4; i++) {
        const int hl = hq + i * 4 + fq;
        const float ae = A_e[bn * 32 + hl];
#pragma unroll
        for (int j = 0; j < 4; j++) {
            const int tl = wt + j * 16 + fr;
            f32x4 v = acc[i][j];
            float bx = v[0] * v[1];
            float sig = 1.0f / (1.0f + __expf(-v[3]));
            epL[tl * 36 + hl] = ((u32)f2bf(sig * ae) << 16) | (u32)f2bf(bx);
            epC[tl * 40 + hl] = f2bf(v[2]);
        }
    }
    __syncthreads();

    // packed store-back: LABX 16 KB -> 4 iters, CC 8 KB -> 2 iters
#pragma unroll
    for (int it = 0; it < 4; it++) {
        const int g = it * 256 + tid;
        const int row = g >> 3, cs = g & 7;
        uint4 v = *(const uint4*)&epL[row * 36 + cs * 4];
        *(uint4*)(LABX + (size_t)(m0t + row) * HID + bn * 32 + cs * 4) = v;
    }
#pragma unroll
    for (int it = 0; it < 2; it++) {
        const int g = it * 256 + tid;
        const int row = g >> 2, cs = g & 3;
        uint4 v = *(const uint4*)&epC[row * 40 + cs * 8];
        *(uint4*)(CCg + (size_t)(m0t + row) * HID + bn * 32 + cs * 8) = v;
    }

    // fused scan pass1: 8 segments x 16 steps, then serial combine
    {
        const int hi  = tid & 31;
        const int seg = tid >> 5;
        float p = 1.f, s = 0.f;
        const int tbase = seg * 16;
#pragma unroll
        for (int t = 0; t < 16; t++) {
            u32 w = epL[(tbase + t) * 36 + hi];
            float a  = exp2f(bf2f((u16)(w >> 16)));
            float bx = bf2f((u16)(w & 0xffff));
            s = fmaf(a, s, bx);
            p *= a;
        }
        Ps[seg * 32 + hi] = p;
        Ss[seg * 32 + hi] = s;
        __syncthreads();
        if (tid < 32) {
            float pt = 1.f, st = 0.f;
#pragma unroll
            for (int sg = 0; sg < 8; sg++) {
                float ps = Ps[sg * 32 + tid], ss = Ss[sg * 32 + tid];
                st = fmaf(ps, st, ss);
                pt *= ps;
            }
            P[(size_t)bm * HID + bn * 32 + tid] = pt;
            S[(size_t)bm * HID + bn * 32 + tid] = st;
        }
    }
}

// ---------------------------------------------------------------------------
// Kernel 4: sequential combine across 64 chunks per channel -> H0[c,h]
// ---------------------------------------------------------------------------
__global__ void scan_combine(const float* __restrict__ P,
                             const float* __restrict__ S,
                             float* __restrict__ H0)
{
    const int h = blockIdx.x * 256 + threadIdx.x;
    float hrun = 0.f;
    for (int c = 0; c < NCH; c++) {
        H0[c * HID + h] = hrun;
        hrun = fmaf(P[c * HID + h], hrun, S[c * HID + h]);
    }
}

// ---------------------------------------------------------------------------
// Kernel 5: fused pass2 + output GEMM.
// Block = (chunk c, hgroup of 256 h). Phase 1: scan 128 t, y -> LDS (bf16,
// XOR-swizzled col groups: phys = (g ^ (t&7))<<3 | lo). Phase 2: MFMA
// (A = W_out bf16 frags [o x k], B = y frags [t x k]) -> atomicAdd out.
// ---------------------------------------------------------------------------
__launch_bounds__(256)
__global__ void scan_out(const u32* __restrict__ LABX,
                         const u16* __restrict__ CCg,
                         const float* __restrict__ H0,
                         const float* __restrict__ W_out,
                         float* __restrict__ out)
{
    __shared__ __align__(16) u16 ybuf[128 * 256];   // 64 KB
    const int tid  = threadIdx.x;
    const int c    = blockIdx.x >> 3;
    const int hg   = blockIdx.x & 7;
    const int lane = tid & 63;
    const int wave = tid >> 6;
    const int fr   = lane & 15;
    const int fq   = lane >> 4;

    // preload W_out A-frags: lane fr = o (rows 8..15 zero), k = fq*8 + j
    bf16x8 bw[8];
#pragma unroll
    for (int ks = 0; ks < 8; ks++) {
        bf16x8 w;
#pragma unroll
        for (int j = 0; j < 8; j++) {
            const int hb = hg * 256 + ks * 32 + fq * 8 + j;
            u16 v = (fr < 8) ? f2bf(W_out[(size_t)fr * HID + hb]) : (u16)0;
            w[j] = (short)v;
        }
        bw[ks] = w;
    }

    // phase 1: scan
    const int h = hg * 256 + tid;
    float hrun = H0[c * HID + h];
    size_t base = ((size_t)c * CT) * HID + h;
    const int g  = tid >> 3;
    const int lo = tid & 7;
    for (int t = 0; t < CT; t++) {
        u32 wv   = LABX[base];
        float bx = bf2f((u16)(wv & 0xffff));
        float a  = exp2f(bf2f((u16)(wv >> 16)));
        float cc = bf2f(CCg[base]);
        hrun = fmaf(a, hrun, bx);
        ybuf[t * 256 + (((g ^ (t & 7)) << 3) | lo)] = f2bf(cc * hrun);
        base += HID;
    }
    __syncthreads();

    // phase 2: per wave, 2 m-tiles of 16 t; D row (4fq+reg) = o, col fr = t
#pragma unroll
    for (int mt = 0; mt < 2; mt++) {
        const int tb = wave * 32 + mt * 16;
        const int t  = tb + fr;          // this lane's y row (B free index)
        f32x4 acc2 = {0.f, 0.f, 0.f, 0.f};
#pragma unroll
        for (int ks = 0; ks < 8; ks++) {
            const int gg = ks * 4 + fq;
            bf16x8 yv = *(const bf16x8*)
                &ybuf[t * 256 + ((gg ^ (fr & 7)) << 3)];
            acc2 = __builtin_amdgcn_mfma_f32_16x16x32_bf16(bw[ks], yv, acc2,
                                                           0, 0, 0);
        }
        if (fq < 2) {
            const int tg = c * CT + tb + fr;
#pragma unroll
            for (int reg = 0; reg < 4; reg++)
                atomicAdd(&out[(size_t)tg * NOBJ + 4 * fq + reg], acc2[reg]);
        }
    }
}

// ---------------------------------------------------------------------------
extern "C" void kernel_launch(void* const* d_in, const int* in_sizes, int n_in,
                              void* d_out, int out_size, void* d_ws, size_t ws_size,
                              hipStream_t stream)
{
    const float* x      = (const float*)d_in[0];
    const float* Win    = (const float*)d_in[1];
    const float* WB     = (const float*)d_in[2];
    const float* WC     = (const float*)d_in[3];
    const float* Wd     = (const float*)d_in[4];
    const float* A_log  = (const float*)d_in[5];
    const float* W_out  = (const float*)d_in[6];
    const float* b_out  = (const float*)d_in[7];
    const float* W_skip = (const float*)d_in[8];
    float* out = (float*)d_out;

    char* ws = (char*)d_ws;
    size_t off = 0;
    auto alloc = [&](size_t bytes) -> void* {
        void* p = (void*)(ws + off);
        off += (bytes + 255) & ~(size_t)255;
        return p;
    };

    u16*   x_bf = (u16*)  alloc((size_t)TT * KOBS * 2);        //  8.4 MB
    u16*   W_bf = (u16*)  alloc((size_t)4 * HID * KOBS * 2);   //  8.4 MB
    float* A_e  = (float*)alloc((size_t)HID * 4);
    u32*   LABX = (u32*)  alloc((size_t)TT * HID * 4);         // 67.1 MB
    u16*   CCg  = (u16*)  alloc((size_t)TT * HID * 2);         // 33.6 MB
    float* P    = (float*)alloc((size_t)NCH * HID * 4);
    float* S    = (float*)alloc((size_t)NCH * HID * 4);
    float* H0   = (float*)alloc((size_t)NCH * HID * 4);
    (void)ws_size; (void)in_sizes; (void)n_in; (void)out_size;

    prep_kernel<<<2048, 256, 0, stream>>>(x, Win, WB, WC, Wd, A_log,
                                          x_bf, W_bf, A_e);
    init_out<<<512, 256, 0, stream>>>(x, b_out, W_skip, out);
    gemm_fused<<<4096, 256, 0, stream>>>(x_bf, W_bf, A_e, LABX, CCg, P, S);
    scan_combine<<<8, 256, 0, stream>>>(P, S, H0);
    scan_out<<<512, 256, 0, stream>>>(LABX, CCg, H0, W_out, out);
}

// Round 5
// 221.980 us; speedup vs baseline: 1.0935x; 1.0935x over previous
//
#include <hip/hip_runtime.h>
#include <hip/hip_bf16.h>
#include <cstdint>

#define TT   8192
#define KOBS 512
#define HID  2048
#define NOBJ 8
#define NCH  64     // number of time chunks
#define CT   128    // chunk length (TT / NCH)

typedef unsigned short u16;
typedef uint32_t u32;
typedef short bf16x8 __attribute__((ext_vector_type(8)));
typedef float f32x4  __attribute__((ext_vector_type(4)));
typedef unsigned short u16x4 __attribute__((ext_vector_type(4)));

static __device__ __forceinline__ float bf2f(u16 u) {
    union { uint32_t i; float f; } v;
    v.i = ((uint32_t)u) << 16;
    return v.f;
}
static __device__ __forceinline__ u16 f2bf(float f) {
    union { float f; uint32_t i; } v;
    v.f = f;
    uint32_t lsb = (v.i >> 16) & 1u;
    uint32_t r = v.i + 0x7fffu + lsb;   // round-to-nearest-even
    return (u16)(r >> 16);
}

// async global->LDS DMA, 16 bytes per lane (wave-uniform base + lane*16).
static __device__ __forceinline__ void async_ld16(const u16* g, u16* l) {
    __builtin_amdgcn_global_load_lds(
        (const __attribute__((address_space(1))) uint32_t*)g,
        (__attribute__((address_space(3))) uint32_t*)l,
        16, 0, 0);
}

// ---------------------------------------------------------------------------
// Kernel 1: vectorized cast x -> bf16; cast + row-interleave the 4 weight
// matrices (row n = 4*h + proj); A_e[h] = -exp(A_log[h]) * log2(e).
// ---------------------------------------------------------------------------
__global__ void prep_kernel(const float* __restrict__ x,
                            const float* __restrict__ Win,
                            const float* __restrict__ WB,
                            const float* __restrict__ WC,
                            const float* __restrict__ Wd,
                            const float* __restrict__ A_log,
                            u16* __restrict__ x_bf,
                            u16* __restrict__ W_bf,
                            float* __restrict__ A_e)
{
    const int tid0   = blockIdx.x * blockDim.x + threadIdx.x;
    const int stride = gridDim.x * blockDim.x;       // 524288

    // x: 1,048,576 float4 -> 2 iters
    const float4* x4 = (const float4*)x;
    for (int i = tid0; i < TT * KOBS / 4; i += stride) {
        float4 v = x4[i];
        u16x4 o = { f2bf(v.x), f2bf(v.y), f2bf(v.z), f2bf(v.w) };
        *(u16x4*)&x_bf[(size_t)i * 4] = o;
    }

    // W: 524,288 groups of 8 -> 1 iter; 64 consecutive i share row n
    for (int i = tid0; i < 4 * HID * KOBS / 8; i += stride) {
        int n  = i >> 6;
        int k8 = (i & 63) * 8;
        int h  = n >> 2;
        int w  = n & 3;
        const float* src = (w == 0) ? Win : (w == 1) ? WB : (w == 2) ? WC : Wd;
        const float4* s4 = (const float4*)(src + (size_t)h * KOBS + k8);
        float4 a = s4[0], b = s4[1];
        u16x4 o1 = { f2bf(a.x), f2bf(a.y), f2bf(a.z), f2bf(a.w) };
        u16x4 o2 = { f2bf(b.x), f2bf(b.y), f2bf(b.z), f2bf(b.w) };
        *(u16x4*)&W_bf[(size_t)i * 8]     = o1;
        *(u16x4*)&W_bf[(size_t)i * 8 + 4] = o2;
    }

    if (tid0 < HID)
        A_e[tid0] = -__expf(A_log[tid0]) * 1.44269504f;
}

// ---------------------------------------------------------------------------
// Kernel 2: out[t,:] = b_out + x[t,:] @ W_skip.T   (base for atomics)
// ---------------------------------------------------------------------------
__launch_bounds__(256)
__global__ void init_out(const float* __restrict__ x,
                         const float* __restrict__ b_out,
                         const float* __restrict__ W_skip,
                         float* __restrict__ out)
{
    const int wave = threadIdx.x >> 6;
    const int lane = threadIdx.x & 63;
    const int t0 = (blockIdx.x * 4 + wave) * 4;

    float acc[4][NOBJ];
#pragma unroll
    for (int tt = 0; tt < 4; tt++)
#pragma unroll
        for (int o = 0; o < NOBJ; o++) acc[tt][o] = 0.f;

#pragma unroll
    for (int i = 0; i < 2; i++) {
        const int kv = (i * 64 + lane) * 4;
        float4 w[NOBJ];
#pragma unroll
        for (int o = 0; o < NOBJ; o++)
            w[o] = *(const float4*)(W_skip + (size_t)o * KOBS + kv);
#pragma unroll
        for (int tt = 0; tt < 4; tt++) {
            float4 xv = *(const float4*)(x + (size_t)(t0 + tt) * KOBS + kv);
#pragma unroll
            for (int o = 0; o < NOBJ; o++)
                acc[tt][o] += xv.x * w[o].x + xv.y * w[o].y +
                              xv.z * w[o].z + xv.w * w[o].w;
        }
    }
#pragma unroll
    for (int s = 32; s > 0; s >>= 1)
#pragma unroll
        for (int tt = 0; tt < 4; tt++)
#pragma unroll
            for (int o = 0; o < NOBJ; o++)
                acc[tt][o] += __shfl_xor(acc[tt][o], s, 64);
    if (lane == 0) {
#pragma unroll
        for (int tt = 0; tt < 4; tt++)
#pragma unroll
            for (int o = 0; o < NOBJ; o++)
                out[(size_t)(t0 + tt) * NOBJ + o] = acc[tt][o] + b_out[o];
    }
}

// ---------------------------------------------------------------------------
// Kernel 3: fused GEMM + elementwise + scan-pass1  (round-3 proven version:
// 84 VGPR, occupancy ~29%, 106 us).
// A operand = W rows (n-dim) -> D row (4fq+reg) = n, reg = projection.
// ---------------------------------------------------------------------------
__launch_bounds__(256)
__global__ void gemm_fused(const u16* __restrict__ x_bf,
                           const u16* __restrict__ W_bf,
                           const float* __restrict__ A_e,
                           u16* __restrict__ BX,
                           u16* __restrict__ CC,
                           u16* __restrict__ LA,
                           float* __restrict__ P,
                           float* __restrict__ S)
{
    // union: K-loop staging (16 KB) / epilogue transpose buffer (30 KB)
    __shared__ __align__(16) u16 smem[3 * 128 * 40];   // 30720 B
    __shared__ float Ps[256], Ss[256];                 //  2 KB
    u16* a_s = smem;            // x tile: 128 t-rows x 32 k
    u16* b_s = smem + 4096;     // W tile: 128 n-rows x 32 k

    const int tid  = threadIdx.x;
    const int bm   = blockIdx.x & 63;    // t-chunk (== scan chunk c)
    const int bn   = blockIdx.x >> 6;    // channel group (32 h)
    const int m0t  = bm * 128;
    const int n0   = bn * 128;
    const int lane = tid & 63;
    const int wave = tid >> 6;
    const int wn   = (wave & 1) * 64;    // n-dim wave offset
    const int wt   = (wave >> 1) * 64;   // t-dim wave offset
    const int fr   = lane & 15;
    const int fq   = lane >> 4;

    f32x4 acc[4][4];
#pragma unroll
    for (int i = 0; i < 4; i++)
#pragma unroll
        for (int j = 0; j < 4; j++) {
            f32x4 z = {0.f, 0.f, 0.f, 0.f};
            acc[i][j] = z;
        }

    const int srow = tid >> 2;                       // 0..63
    const int scg  = (tid & 3) ^ ((srow >> 1) & 3);  // XOR col-group swizzle
    const u16* gA0 = x_bf + (size_t)(m0t + srow) * KOBS + scg * 8;
    const u16* gA1 = gA0 + (size_t)64 * KOBS;
    const u16* gB0 = W_bf + (size_t)(n0 + srow) * KOBS + scg * 8;
    const u16* gB1 = gB0 + (size_t)64 * KOBS;
    u16* lA0 = &a_s[tid * 8];
    u16* lA1 = &a_s[2048 + tid * 8];
    u16* lB0 = &b_s[tid * 8];
    u16* lB1 = &b_s[2048 + tid * 8];

    const int pcg = fq ^ ((fr >> 1) & 3);  // fragment-read swizzled col-group

    for (int kb = 0; kb < KOBS; kb += 32) {
        async_ld16(gA0 + kb, lA0);
        async_ld16(gA1 + kb, lA1);
        async_ld16(gB0 + kb, lB0);
        async_ld16(gB1 + kb, lB1);
        __syncthreads();

        bf16x8 af[4], bfx[4];
#pragma unroll
        for (int i = 0; i < 4; i++)    // A operand = W rows (n-dim)
            af[i] = *(const bf16x8*)&b_s[(wn + i * 16 + fr) * 32 + pcg * 8];
#pragma unroll
        for (int j = 0; j < 4; j++)    // B operand = x rows (t-dim)
            bfx[j] = *(const bf16x8*)&a_s[(wt + j * 16 + fr) * 32 + pcg * 8];

#pragma unroll
        for (int i = 0; i < 4; i++)
#pragma unroll
            for (int j = 0; j < 4; j++)
                acc[i][j] = __builtin_amdgcn_mfma_f32_16x16x32_bf16(
                    af[i], bfx[j], acc[i][j], 0, 0, 0);
        __syncthreads();
    }

    // ---- epilogue: D row = wn + i*16 + 4*fq + reg (reg=proj), col = wt+j*16+fr
    const int hq = wn >> 2;                  // 0 or 16
#pragma unroll
    for (int i = 0; i < 4; i++) {
        const int hl = hq + i * 4 + fq;      // h_local 0..31
        const float ae = A_e[bn * 32 + hl];
#pragma unroll
        for (int j = 0; j < 4; j++) {
            const int tl = wt + j * 16 + fr;
            f32x4 v = acc[i][j];
            float sig = 1.0f / (1.0f + __expf(-v[3]));
            smem[(0 * 128 + tl) * 40 + hl] = f2bf(v[0] * v[1]);  // BX
            smem[(1 * 128 + tl) * 40 + hl] = f2bf(v[2]);         // CC
            smem[(2 * 128 + tl) * 40 + hl] = f2bf(sig * ae);     // LA
        }
    }
    __syncthreads();

    // ---- packed global stores: 384 chunks (a,t) of 64 B, 6 iters
#pragma unroll
    for (int it = 0; it < 6; it++) {
        const int g = it * 64 + (tid >> 2);
        const int a = g >> 7;
        const int t = g & 127;
        const int c = tid & 3;
        uint4 vd = *(const uint4*)&smem[(a * 128 + t) * 40 + c * 8];
        u16* dst = (a == 0 ? BX : (a == 1 ? CC : LA)) +
                   (size_t)(m0t + t) * HID + bn * 32 + c * 8;
        *(uint4*)dst = vd;
    }

    // ---- fused scan pass1: 8 segments x 16 steps, then serial combine
    {
        const int hi  = tid & 31;
        const int seg = tid >> 5;
        float p = 1.f, s = 0.f;
        const int tbase = seg * 16;
#pragma unroll
        for (int t = 0; t < 16; t++) {
            float a  = exp2f(bf2f(smem[(2 * 128 + tbase + t) * 40 + hi]));
            float bx = bf2f(smem[(0 * 128 + tbase + t) * 40 + hi]);
            s = fmaf(a, s, bx);
            p *= a;
        }
        Ps[seg * 32 + hi] = p;
        Ss[seg * 32 + hi] = s;
        __syncthreads();
        if (tid < 32) {
            float pt = 1.f, st = 0.f;
#pragma unroll
            for (int sg = 0; sg < 8; sg++) {
                float ps = Ps[sg * 32 + tid], ss = Ss[sg * 32 + tid];
                st = fmaf(ps, st, ss);
                pt *= ps;
            }
            P[(size_t)bm * HID + bn * 32 + tid] = pt;
            S[(size_t)bm * HID + bn * 32 + tid] = st;
        }
    }
}

// ---------------------------------------------------------------------------
// Kernel 4: sequential combine across 64 chunks per channel -> H0[c,h]
// (loads are independent across c -> unroll for deep prefetch)
// ---------------------------------------------------------------------------
__global__ void scan_combine(const float* __restrict__ P,
                             const float* __restrict__ S,
                             float* __restrict__ H0)
{
    const int h = blockIdx.x * 256 + threadIdx.x;
    float hrun = 0.f;
#pragma unroll 8
    for (int c = 0; c < NCH; c++) {
        H0[c * HID + h] = hrun;
        hrun = fmaf(P[c * HID + h], hrun, S[c * HID + h]);
    }
}

// ---------------------------------------------------------------------------
// Kernel 5: fused pass2 + output GEMM (structure HW-validated in round 4).
// Phase 1: scan 128 t, y -> LDS (bf16, XOR-swizzled col groups), with
// 4-deep load batching. Phase 2: MFMA (A = W_out bf16 frags staged through
// LDS coalesced, B = y frags) -> atomicAdd into out.
// ---------------------------------------------------------------------------
__launch_bounds__(256)
__global__ void scan_out(const u16* __restrict__ LA,
                         const u16* __restrict__ BX,
                         const u16* __restrict__ CC,
                         const float* __restrict__ H0,
                         const float* __restrict__ W_out,
                         float* __restrict__ out)
{
    __shared__ __align__(16) u16 ybuf[128 * 256];   // 64 KB
    __shared__ float wst[8 * 260];                  // 8.3 KB, pad vs 16-way
    const int tid  = threadIdx.x;
    const int c    = blockIdx.x >> 3;
    const int hg   = blockIdx.x & 7;
    const int lane = tid & 63;
    const int wave = tid >> 6;
    const int fr   = lane & 15;
    const int fq   = lane >> 4;

    // stage W_out slice coalesced (8 KB)
#pragma unroll
    for (int o = 0; o < 8; o++)
        wst[o * 260 + tid] = W_out[(size_t)o * HID + hg * 256 + tid];

    // phase 1: scan with 4-deep load batching
    const int h = hg * 256 + tid;
    float hrun = H0[c * HID + h];
    size_t base = ((size_t)c * CT) * HID + h;
    const int g  = tid >> 3;
    const int lo = tid & 7;
    for (int tb = 0; tb < CT; tb += 4) {
        u16 la4[4], bx4[4], cc4[4];
#pragma unroll
        for (int q = 0; q < 4; q++) {
            la4[q] = LA[base + (size_t)q * HID];
            bx4[q] = BX[base + (size_t)q * HID];
            cc4[q] = CC[base + (size_t)q * HID];
        }
#pragma unroll
        for (int q = 0; q < 4; q++) {
            float a = exp2f(bf2f(la4[q]));
            hrun = fmaf(a, hrun, bf2f(bx4[q]));
            const int t = tb + q;
            ybuf[t * 256 + (((g ^ (t & 7)) << 3) | lo)] = f2bf(bf2f(cc4[q]) * hrun);
        }
        base += (size_t)4 * HID;
    }
    __syncthreads();

    // build W_out A-frags from LDS: lane fr = o (rows 8..15 zero), k = fq*8+j
    bf16x8 bw[8];
#pragma unroll
    for (int ks = 0; ks < 8; ks++) {
        bf16x8 w;
#pragma unroll
        for (int j = 0; j < 8; j++) {
            u16 v = (fr < 8) ? f2bf(wst[fr * 260 + ks * 32 + fq * 8 + j])
                             : (u16)0;
            w[j] = (short)v;
        }
        bw[ks] = w;
    }

    // phase 2: per wave, 2 m-tiles of 16 t; D row (4fq+reg) = o, col fr = t
#pragma unroll
    for (int mt = 0; mt < 2; mt++) {
        const int tb = wave * 32 + mt * 16;
        const int t  = tb + fr;
        f32x4 acc2 = {0.f, 0.f, 0.f, 0.f};
#pragma unroll
        for (int ks = 0; ks < 8; ks++) {
            const int gg = ks * 4 + fq;
            bf16x8 yv = *(const bf16x8*)
                &ybuf[t * 256 + ((gg ^ (fr & 7)) << 3)];
            acc2 = __builtin_amdgcn_mfma_f32_16x16x32_bf16(bw[ks], yv, acc2,
                                                           0, 0, 0);
        }
        if (fq < 2) {
            const int tg = c * CT + tb + fr;
#pragma unroll
            for (int reg = 0; reg < 4; reg++)
                atomicAdd(&out[(size_t)tg * NOBJ + 4 * fq + reg], acc2[reg]);
        }
    }
}

// ---------------------------------------------------------------------------
extern "C" void kernel_launch(void* const* d_in, const int* in_sizes, int n_in,
                              void* d_out, int out_size, void* d_ws, size_t ws_size,
                              hipStream_t stream)
{
    const float* x      = (const float*)d_in[0];
    const float* Win    = (const float*)d_in[1];
    const float* WB     = (const float*)d_in[2];
    const float* WC     = (const float*)d_in[3];
    const float* Wd     = (const float*)d_in[4];
    const float* A_log  = (const float*)d_in[5];
    const float* W_out  = (const float*)d_in[6];
    const float* b_out  = (const float*)d_in[7];
    const float* W_skip = (const float*)d_in[8];
    float* out = (float*)d_out;

    char* ws = (char*)d_ws;
    size_t off = 0;
    auto alloc = [&](size_t bytes) -> void* {
        void* p = (void*)(ws + off);
        off += (bytes + 255) & ~(size_t)255;
        return p;
    };

    u16*   x_bf = (u16*)  alloc((size_t)TT * KOBS * 2);        //  8.4 MB
    u16*   W_bf = (u16*)  alloc((size_t)4 * HID * KOBS * 2);   //  8.4 MB
    float* A_e  = (float*)alloc((size_t)HID * 4);
    u16*   LA   = (u16*)  alloc((size_t)TT * HID * 2);         // 33.6 MB
    u16*   BX   = (u16*)  alloc((size_t)TT * HID * 2);         // 33.6 MB
    u16*   CC   = (u16*)  alloc((size_t)TT * HID * 2);         // 33.6 MB
    float* P    = (float*)alloc((size_t)NCH * HID * 4);
    float* S    = (float*)alloc((size_t)NCH * HID * 4);
    float* H0   = (float*)alloc((size_t)NCH * HID * 4);
    (void)ws_size; (void)in_sizes; (void)n_in; (void)out_size;

    prep_kernel<<<2048, 256, 0, stream>>>(x, Win, WB, WC, Wd, A_log,
                                          x_bf, W_bf, A_e);
    init_out<<<512, 256, 0, stream>>>(x, b_out, W_skip, out);
    gemm_fused<<<4096, 256, 0, stream>>>(x_bf, W_bf, A_e, BX, CC, LA, P, S);
    scan_combine<<<8, 256, 0, stream>>>(P, S, H0);
    scan_out<<<512, 256, 0, stream>>>(LA, BX, CC, H0, W_out, out);
}